// Round 2
// baseline (9433.939 us; speedup 1.0000x reference)
//
#include <hip/hip_runtime.h>

#define HORIZON 28
#define GAMMA 0.1f

__global__ void __launch_bounds__(256) sir_kernel(
    const float* __restrict__ inputs,
    const float* __restrict__ W1,
    const float* __restrict__ b1,
    const float* __restrict__ W2,
    const float* __restrict__ b2,
    const float* __restrict__ W3,
    const float* __restrict__ b3,
    float* __restrict__ out,
    int nrows)
{
    __shared__ float sW1[96];    // [3][32] row-major
    __shared__ float sB1[32];
    __shared__ float sW2[512];   // [32][16] row-major
    __shared__ float sB2[16];
    __shared__ float sW3[16];

    const int tid = threadIdx.x;
    if (tid < 96) sW1[tid] = W1[tid];
    if (tid >= 96 && tid < 128) sB1[tid - 96] = b1[tid - 96];
    if (tid >= 128 && tid < 144) sB2[tid - 128] = b2[tid - 128];
    if (tid >= 144 && tid < 160) sW3[tid - 144] = W3[tid - 144];
    sW2[tid] = W2[tid];
    sW2[tid + 256] = W2[tid + 256];
    const float b3v = b3[0];
    __syncthreads();

    const int row = blockIdx.x * 256 + tid;
    if (row >= nrows) return;

    const float* p = inputs + ((long)row * 8 + 7) * 3;
    float s  = p[0];
    float iv = p[1];
    float r  = p[2];
    const float rcpN = 1.0f / (s + iv + r);   // N is conserved by the SIR update

    auto step1 = [&]() -> float {
        // layer 1: 3 -> 32, relu
        float h1[32];
        #pragma unroll
        for (int j = 0; j < 32; ++j) {
            float v = fmaf(s, sW1[j], sB1[j]);
            v = fmaf(iv, sW1[32 + j], v);
            v = fmaf(r,  sW1[64 + j], v);
            h1[j] = fmaxf(v, 0.0f);
        }
        // layer 2: 32 -> 16 (k-outer so W2 reads are contiguous float4 / b128)
        float h2[16];
        #pragma unroll
        for (int n = 0; n < 16; ++n) h2[n] = sB2[n];
        #pragma unroll
        for (int k = 0; k < 32; ++k) {
            const float a = h1[k];
            const float4 w0 = *reinterpret_cast<const float4*>(&sW2[k * 16 + 0]);
            const float4 w1 = *reinterpret_cast<const float4*>(&sW2[k * 16 + 4]);
            const float4 w2 = *reinterpret_cast<const float4*>(&sW2[k * 16 + 8]);
            const float4 w3 = *reinterpret_cast<const float4*>(&sW2[k * 16 + 12]);
            h2[0]  = fmaf(a, w0.x, h2[0]);
            h2[1]  = fmaf(a, w0.y, h2[1]);
            h2[2]  = fmaf(a, w0.z, h2[2]);
            h2[3]  = fmaf(a, w0.w, h2[3]);
            h2[4]  = fmaf(a, w1.x, h2[4]);
            h2[5]  = fmaf(a, w1.y, h2[5]);
            h2[6]  = fmaf(a, w1.z, h2[6]);
            h2[7]  = fmaf(a, w1.w, h2[7]);
            h2[8]  = fmaf(a, w2.x, h2[8]);
            h2[9]  = fmaf(a, w2.y, h2[9]);
            h2[10] = fmaf(a, w2.z, h2[10]);
            h2[11] = fmaf(a, w2.w, h2[11]);
            h2[12] = fmaf(a, w3.x, h2[12]);
            h2[13] = fmaf(a, w3.y, h2[13]);
            h2[14] = fmaf(a, w3.z, h2[14]);
            h2[15] = fmaf(a, w3.w, h2[15]);
        }
        // layer 3: 16 -> 1 (relu folded in)
        float z = b3v;
        #pragma unroll
        for (int n = 0; n < 16; ++n) z = fmaf(fmaxf(h2[n], 0.0f), sW3[n], z);
        // softplus (stable): max(z,0) + log(1 + exp(-|z|))
        const float beta = fmaxf(z, 0.0f) + __logf(1.0f + __expf(-fabsf(z)));
        // SIR update
        const float new_inf = beta * s * iv * rcpN;
        const float new_rec = GAMMA * iv;
        s  = s - new_inf;
        iv = iv + new_inf - new_rec;
        r  = r + new_rec;
        return iv;
    };

    const long obase = (long)row * HORIZON;
    #pragma unroll 1
    for (int tt = 0; tt < HORIZON / 4; ++tt) {
        float4 o;
        o.x = step1();
        o.y = step1();
        o.z = step1();
        o.w = step1();
        *reinterpret_cast<float4*>(out + obase + tt * 4) = o;
    }
}

extern "C" void kernel_launch(void* const* d_in, const int* in_sizes, int n_in,
                              void* d_out, int out_size, void* d_ws, size_t ws_size,
                              hipStream_t stream) {
    const float* inputs = (const float*)d_in[0];
    const float* W1 = (const float*)d_in[1];
    const float* b1 = (const float*)d_in[2];
    const float* W2 = (const float*)d_in[3];
    const float* b2 = (const float*)d_in[4];
    const float* W3 = (const float*)d_in[5];
    const float* b3 = (const float*)d_in[6];
    float* out = (float*)d_out;

    const int nrows = in_sizes[0] / 24;   // (B, 8, 3) fp32
    const int grid = (nrows + 255) / 256;
    sir_kernel<<<grid, 256, 0, stream>>>(inputs, W1, b1, W2, b2, W3, b3, out, nrows);
}

// Round 3
// 568.928 us; speedup vs baseline: 16.5820x; 16.5820x over previous
//
#include <hip/hip_runtime.h>

#define HORIZON 28
#define GAMMA 0.1f

__global__ void __launch_bounds__(256) sir_kernel(
    const float* __restrict__ inputs,
    const float* __restrict__ W1,
    const float* __restrict__ b1,
    const float* __restrict__ W2,
    const float* __restrict__ b2,
    const float* __restrict__ W3,
    const float* __restrict__ b3,
    float* __restrict__ out,
    int nrows)
{
    __shared__ float sW1[128];   // packed [32][4] = {W1[0][k], W1[1][k], W1[2][k], b1[k]}
    __shared__ float sW2[512];   // [32][16] row-major
    __shared__ float sB2[16];
    __shared__ float sW3[16];

    const int tid = threadIdx.x;
    if (tid < 32) {
        sW1[tid * 4 + 0] = W1[tid];
        sW1[tid * 4 + 1] = W1[32 + tid];
        sW1[tid * 4 + 2] = W1[64 + tid];
        sW1[tid * 4 + 3] = b1[tid];
    }
    if (tid >= 32 && tid < 48) sB2[tid - 32] = b2[tid - 32];
    if (tid >= 48 && tid < 64) sW3[tid - 48] = W3[tid - 48];
    sW2[tid]       = W2[tid];
    sW2[tid + 256] = W2[tid + 256];
    const float b3v = b3[0];
    __syncthreads();

    const int row = blockIdx.x * 256 + tid;
    if (row >= nrows) return;

    const float* p = inputs + ((long)row * 8 + 7) * 3;
    float s  = p[0];
    float iv = p[1];
    float r  = p[2];
    const float rcpN = 1.0f / (s + iv + r);   // N conserved by the SIR update

    auto step1 = [&]() -> float {
        // fused layer1+layer2: h1_k consumed immediately, never a live array
        float h2[16];
        #pragma unroll
        for (int n = 0; n < 16; ++n) h2[n] = sB2[n];
        #pragma unroll 4   // cap hoisted LDS loads -> no VGPR blow-up / spill
        for (int k = 0; k < 32; ++k) {
            const float4 wp = *reinterpret_cast<const float4*>(&sW1[k * 4]);
            float v = fmaf(s, wp.x, wp.w);
            v = fmaf(iv, wp.y, v);
            v = fmaf(r,  wp.z, v);
            const float a = fmaxf(v, 0.0f);
            const float4 w0 = *reinterpret_cast<const float4*>(&sW2[k * 16 + 0]);
            const float4 w1 = *reinterpret_cast<const float4*>(&sW2[k * 16 + 4]);
            const float4 w2 = *reinterpret_cast<const float4*>(&sW2[k * 16 + 8]);
            const float4 w3 = *reinterpret_cast<const float4*>(&sW2[k * 16 + 12]);
            h2[0]  = fmaf(a, w0.x, h2[0]);
            h2[1]  = fmaf(a, w0.y, h2[1]);
            h2[2]  = fmaf(a, w0.z, h2[2]);
            h2[3]  = fmaf(a, w0.w, h2[3]);
            h2[4]  = fmaf(a, w1.x, h2[4]);
            h2[5]  = fmaf(a, w1.y, h2[5]);
            h2[6]  = fmaf(a, w1.z, h2[6]);
            h2[7]  = fmaf(a, w1.w, h2[7]);
            h2[8]  = fmaf(a, w2.x, h2[8]);
            h2[9]  = fmaf(a, w2.y, h2[9]);
            h2[10] = fmaf(a, w2.z, h2[10]);
            h2[11] = fmaf(a, w2.w, h2[11]);
            h2[12] = fmaf(a, w3.x, h2[12]);
            h2[13] = fmaf(a, w3.y, h2[13]);
            h2[14] = fmaf(a, w3.z, h2[14]);
            h2[15] = fmaf(a, w3.w, h2[15]);
        }
        // layer 3: 16 -> 1, relu folded in; W3 via float4 reads
        const float4 u0 = *reinterpret_cast<const float4*>(&sW3[0]);
        const float4 u1 = *reinterpret_cast<const float4*>(&sW3[4]);
        const float4 u2 = *reinterpret_cast<const float4*>(&sW3[8]);
        const float4 u3 = *reinterpret_cast<const float4*>(&sW3[12]);
        float z = b3v;
        z = fmaf(fmaxf(h2[0],  0.0f), u0.x, z);
        z = fmaf(fmaxf(h2[1],  0.0f), u0.y, z);
        z = fmaf(fmaxf(h2[2],  0.0f), u0.z, z);
        z = fmaf(fmaxf(h2[3],  0.0f), u0.w, z);
        z = fmaf(fmaxf(h2[4],  0.0f), u1.x, z);
        z = fmaf(fmaxf(h2[5],  0.0f), u1.y, z);
        z = fmaf(fmaxf(h2[6],  0.0f), u1.z, z);
        z = fmaf(fmaxf(h2[7],  0.0f), u1.w, z);
        z = fmaf(fmaxf(h2[8],  0.0f), u2.x, z);
        z = fmaf(fmaxf(h2[9],  0.0f), u2.y, z);
        z = fmaf(fmaxf(h2[10], 0.0f), u2.z, z);
        z = fmaf(fmaxf(h2[11], 0.0f), u2.w, z);
        z = fmaf(fmaxf(h2[12], 0.0f), u3.x, z);
        z = fmaf(fmaxf(h2[13], 0.0f), u3.y, z);
        z = fmaf(fmaxf(h2[14], 0.0f), u3.z, z);
        z = fmaf(fmaxf(h2[15], 0.0f), u3.w, z);
        // softplus (stable): max(z,0) + log(1 + exp(-|z|))
        const float beta = fmaxf(z, 0.0f) + __logf(1.0f + __expf(-fabsf(z)));
        // SIR update
        const float new_inf = beta * s * iv * rcpN;
        const float new_rec = GAMMA * iv;
        s  = s - new_inf;
        iv = iv + new_inf - new_rec;
        r  = r + new_rec;
        return iv;
    };

    const long obase = (long)row * HORIZON;
    #pragma unroll 1
    for (int tt = 0; tt < HORIZON / 4; ++tt) {
        float4 o;
        o.x = step1();
        o.y = step1();
        o.z = step1();
        o.w = step1();
        *reinterpret_cast<float4*>(out + obase + tt * 4) = o;
    }
}

extern "C" void kernel_launch(void* const* d_in, const int* in_sizes, int n_in,
                              void* d_out, int out_size, void* d_ws, size_t ws_size,
                              hipStream_t stream) {
    const float* inputs = (const float*)d_in[0];
    const float* W1 = (const float*)d_in[1];
    const float* b1 = (const float*)d_in[2];
    const float* W2 = (const float*)d_in[3];
    const float* b2 = (const float*)d_in[4];
    const float* W3 = (const float*)d_in[5];
    const float* b3 = (const float*)d_in[6];
    float* out = (float*)d_out;

    const int nrows = in_sizes[0] / 24;   // (B, 8, 3) fp32
    const int grid = (nrows + 255) / 256;
    sir_kernel<<<grid, 256, 0, stream>>>(inputs, W1, b1, W2, b2, W3, b3, out, nrows);
}

// Round 4
// 474.238 us; speedup vs baseline: 19.8929x; 1.1997x over previous
//
#include <hip/hip_runtime.h>

#define HORIZON 28
#define GAMMA 0.1f
#define ROWS 2   // rows per thread; block of 256 threads handles 512 rows

__global__ void __launch_bounds__(256) sir_kernel(
    const float* __restrict__ inputs,
    const float* __restrict__ W1,
    const float* __restrict__ b1,
    const float* __restrict__ W2,
    const float* __restrict__ b2,
    const float* __restrict__ W3,
    const float* __restrict__ b3,
    float* __restrict__ out,
    int nrows)
{
    __shared__ float sW1[128];   // packed [32][4] = {W1[0][k], W1[1][k], W1[2][k], b1[k]}
    __shared__ float sW2[512];   // [32][16] row-major

    const int tid = threadIdx.x;
    if (tid < 32) {
        sW1[tid * 4 + 0] = W1[tid];
        sW1[tid * 4 + 1] = W1[32 + tid];
        sW1[tid * 4 + 2] = W1[64 + tid];
        sW1[tid * 4 + 3] = b1[tid];
    }
    sW2[tid]       = W2[tid];
    sW2[tid + 256] = W2[tid + 256];

    // wave-uniform params -> scalar loads / SGPR operands
    float c2[16], c3[16];
    #pragma unroll
    for (int n = 0; n < 16; ++n) { c2[n] = b2[n]; c3[n] = W3[n]; }
    const float b3v = b3[0];
    __syncthreads();

    const int row0 = blockIdx.x * (256 * ROWS) + tid;   // this thread: row0, row0+256
    if (row0 >= nrows) return;

    float s[ROWS], iv[ROWS], r[ROWS], rcpN[ROWS];
    #pragma unroll
    for (int q = 0; q < ROWS; ++q) {
        const int row = row0 + q * 256;
        const float* p = inputs + ((long)row * 8 + 7) * 3;
        s[q]  = p[0];
        iv[q] = p[1];
        r[q]  = p[2];
        rcpN[q] = 1.0f / (s[q] + iv[q] + r[q]);   // N conserved by the SIR update
    }

    auto step = [&](float out_i[ROWS]) {
        float h2[ROWS][16];
        #pragma unroll
        for (int q = 0; q < ROWS; ++q)
            #pragma unroll
            for (int n = 0; n < 16; ++n) h2[q][n] = c2[n];

        #pragma unroll 4   // cap hoisted LDS loads -> no VGPR blow-up / spill
        for (int k = 0; k < 32; ++k) {
            const float4 wp = *reinterpret_cast<const float4*>(&sW1[k * 4]);
            const float4 w0 = *reinterpret_cast<const float4*>(&sW2[k * 16 + 0]);
            const float4 w1 = *reinterpret_cast<const float4*>(&sW2[k * 16 + 4]);
            const float4 w2 = *reinterpret_cast<const float4*>(&sW2[k * 16 + 8]);
            const float4 w3 = *reinterpret_cast<const float4*>(&sW2[k * 16 + 12]);
            #pragma unroll
            for (int q = 0; q < ROWS; ++q) {
                float v = fmaf(s[q], wp.x, wp.w);
                v = fmaf(iv[q], wp.y, v);
                v = fmaf(r[q],  wp.z, v);
                const float a = fmaxf(v, 0.0f);
                h2[q][0]  = fmaf(a, w0.x, h2[q][0]);
                h2[q][1]  = fmaf(a, w0.y, h2[q][1]);
                h2[q][2]  = fmaf(a, w0.z, h2[q][2]);
                h2[q][3]  = fmaf(a, w0.w, h2[q][3]);
                h2[q][4]  = fmaf(a, w1.x, h2[q][4]);
                h2[q][5]  = fmaf(a, w1.y, h2[q][5]);
                h2[q][6]  = fmaf(a, w1.z, h2[q][6]);
                h2[q][7]  = fmaf(a, w1.w, h2[q][7]);
                h2[q][8]  = fmaf(a, w2.x, h2[q][8]);
                h2[q][9]  = fmaf(a, w2.y, h2[q][9]);
                h2[q][10] = fmaf(a, w2.z, h2[q][10]);
                h2[q][11] = fmaf(a, w2.w, h2[q][11]);
                h2[q][12] = fmaf(a, w3.x, h2[q][12]);
                h2[q][13] = fmaf(a, w3.y, h2[q][13]);
                h2[q][14] = fmaf(a, w3.z, h2[q][14]);
                h2[q][15] = fmaf(a, w3.w, h2[q][15]);
            }
        }

        #pragma unroll
        for (int q = 0; q < ROWS; ++q) {
            float z = b3v;
            #pragma unroll
            for (int n = 0; n < 16; ++n)
                z = fmaf(fmaxf(h2[q][n], 0.0f), c3[n], z);
            // softplus (stable): max(z,0) + log(1 + exp(-|z|))
            const float beta = fmaxf(z, 0.0f) + __logf(1.0f + __expf(-fabsf(z)));
            const float new_inf = beta * s[q] * iv[q] * rcpN[q];
            const float new_rec = GAMMA * iv[q];
            s[q]  = s[q] - new_inf;
            iv[q] = iv[q] + new_inf - new_rec;
            r[q]  = r[q] + new_rec;
            out_i[q] = iv[q];
        }
    };

    #pragma unroll 1
    for (int tt = 0; tt < HORIZON / 4; ++tt) {
        float o0[ROWS], o1[ROWS], o2[ROWS], o3[ROWS];
        step(o0);
        step(o1);
        step(o2);
        step(o3);
        #pragma unroll
        for (int q = 0; q < ROWS; ++q) {
            float4 v;
            v.x = o0[q]; v.y = o1[q]; v.z = o2[q]; v.w = o3[q];
            *reinterpret_cast<float4*>(out + (long)(row0 + q * 256) * HORIZON + tt * 4) = v;
        }
    }
}

extern "C" void kernel_launch(void* const* d_in, const int* in_sizes, int n_in,
                              void* d_out, int out_size, void* d_ws, size_t ws_size,
                              hipStream_t stream) {
    const float* inputs = (const float*)d_in[0];
    const float* W1 = (const float*)d_in[1];
    const float* b1 = (const float*)d_in[2];
    const float* W2 = (const float*)d_in[3];
    const float* b2 = (const float*)d_in[4];
    const float* W3 = (const float*)d_in[5];
    const float* b3 = (const float*)d_in[6];
    float* out = (float*)d_out;

    const int nrows = in_sizes[0] / 24;   // (B, 8, 3) fp32
    const int rows_per_block = 256 * ROWS;
    const int grid = (nrows + rows_per_block - 1) / rows_per_block;
    sir_kernel<<<grid, 256, 0, stream>>>(inputs, W1, b1, W2, b2, W3, b3, out, nrows);
}

// Round 5
// 298.801 us; speedup vs baseline: 31.5727x; 1.5871x over previous
//
#include <hip/hip_runtime.h>

#define HORIZON 28
#define GAMMA 0.1f

typedef __attribute__((ext_vector_type(8))) short short8;   // 8 bf16 = 4 VGPR (MFMA A/B frag)
typedef __attribute__((ext_vector_type(4))) float f32x4;    // MFMA C/D frag
typedef __attribute__((ext_vector_type(4))) unsigned int u32x4;

union PackU { unsigned int u[4]; short8 s; u32x4 v; };

__global__ void __launch_bounds__(256) sir_kernel(
    const float* __restrict__ inputs,
    const float* __restrict__ W1,
    const float* __restrict__ b1,
    const float* __restrict__ W2,
    const float* __restrict__ b2,
    const float* __restrict__ W3,
    const float* __restrict__ b3,
    float* __restrict__ out,
    int nrows)
{
    __shared__ __align__(16) float sW1[128];   // packed [32][4] = {W1s, W1i, W1r, b1}
    __shared__ u32x4 sH1[4][512];              // per-wave 8KB: hi[64 rows][32 bf16] + lo[...]

    const int tid  = threadIdx.x;
    const int lane = tid & 63;
    const int wid  = tid >> 6;
    const int g    = lane >> 4;    // lane group 0..3 (k-chunk / out-block)
    const int c15  = lane & 15;    // col index (data row within 16-tile)

    if (tid < 32) {
        sW1[tid*4+0] = W1[tid];
        sW1[tid*4+1] = W1[32+tid];
        sW1[tid*4+2] = W1[64+tid];
        sW1[tid*4+3] = b1[tid];
    }
    __syncthreads();

    // --- persistent A-frags: W2 split hi/lo. lane holds A[out=c15][k=g*8+j] = W2[k][c15]
    short8 ahi, alo;
    {
        PackU ph, pl;
        #pragma unroll
        for (int jj = 0; jj < 4; ++jj) {
            const float we = W2[(g*8 + 2*jj    )*16 + c15];
            const float wo = W2[(g*8 + 2*jj + 1)*16 + c15];
            const unsigned int ue = __float_as_uint(we);
            const unsigned int uo = __float_as_uint(wo);
            const float le = we - __uint_as_float(ue & 0xffff0000u);
            const float lo = wo - __uint_as_float(uo & 0xffff0000u);
            ph.u[jj] = __builtin_amdgcn_perm(uo, ue, 0x07060302u);                               // [bf16(we) | bf16(wo)]
            pl.u[jj] = __builtin_amdgcn_perm(__float_as_uint(lo), __float_as_uint(le), 0x07060302u);
        }
        ahi = ph.s; alo = pl.s;
    }
    // C-init (b2) and W3 for this lane's out-block: rows g*4 + 0..3
    const f32x4 b2f = *reinterpret_cast<const f32x4*>(b2 + g*4);
    const f32x4 w3f = *reinterpret_cast<const f32x4*>(W3 + g*4);
    const float b3v = b3[0];

    const int row = blockIdx.x * 256 + tid;
    if (row >= nrows) return;   // never taken at B=2^20 (wave stays intact for MFMA)

    const float* p = inputs + ((long)row * 8 + 7) * 3;
    float s  = p[0];
    float iv = p[1];
    float r  = p[2];
    const float rcpN = 1.0f / (s + iv + r);   // N conserved by SIR update

    char* const hb    = (char*)&sH1[wid][0];
    const int   wxor  = (lane >> 1) & 3;                       // chunk-XOR key (row = lane)
    char* const wbase = hb + lane * 64;                        // this thread's h1 row
    // read: row rr = c15+16m, logical chunk g -> physical g ^ ((rr>>1)&3) = g ^ ((c15>>1)&3)
    const int rdoff = c15 * 64 + (((g ^ ((c15 >> 1) & 3))) << 4);

    auto step = [&]() -> float {
        // --- L1 fused with split+pack+stage, 4 chunks of 8 k (bounded live set)
        #pragma unroll 1
        for (int c = 0; c < 4; ++c) {
            float h[8];
            #pragma unroll
            for (int j = 0; j < 8; ++j) {
                const f32x4 wp = *reinterpret_cast<const f32x4*>(&sW1[(c*8 + j)*4]);
                float v = fmaf(s, wp[0], wp[3]);
                v = fmaf(iv, wp[1], v);
                v = fmaf(r,  wp[2], v);
                h[j] = fmaxf(v, 0.0f);
            }
            PackU ph, pl;
            #pragma unroll
            for (int jj = 0; jj < 4; ++jj) {
                const unsigned int ue = __float_as_uint(h[2*jj]);
                const unsigned int uo = __float_as_uint(h[2*jj+1]);
                const float le = h[2*jj]   - __uint_as_float(ue & 0xffff0000u);
                const float lo = h[2*jj+1] - __uint_as_float(uo & 0xffff0000u);
                ph.u[jj] = __builtin_amdgcn_perm(uo, ue, 0x07060302u);
                pl.u[jj] = __builtin_amdgcn_perm(__float_as_uint(lo), __float_as_uint(le), 0x07060302u);
            }
            const int co = (c ^ wxor) << 4;   // bank-spread chunk swizzle
            *reinterpret_cast<u32x4*>(wbase + co)        = ph.v;
            *reinterpret_cast<u32x4*>(wbase + 4096 + co) = pl.v;
        }

        // --- L2 via MFMA (hi/lo split = fp32-equivalent) + L3 reduce, 4 tiles of 16 rows
        float z[4];
        #pragma unroll
        for (int m = 0; m < 4; ++m) {
            const int ro = rdoff + m * 1024;   // 16 rows * 64 B
            const short8 bh = *reinterpret_cast<const short8*>(hb + ro);
            const short8 bl = *reinterpret_cast<const short8*>(hb + 4096 + ro);
            f32x4 acc = __builtin_amdgcn_mfma_f32_16x16x32_bf16(ahi, bh, b2f, 0, 0, 0);
            acc = __builtin_amdgcn_mfma_f32_16x16x32_bf16(ahi, bl, acc, 0, 0, 0);
            acc = __builtin_amdgcn_mfma_f32_16x16x32_bf16(alo, bh, acc, 0, 0, 0);
            // L3 partial: this lane's 4 h2-outs (rows g*4+reg) for data row 16m+c15
            float pz = fmaxf(acc[0], 0.0f) * w3f[0];
            pz = fmaf(fmaxf(acc[1], 0.0f), w3f[1], pz);
            pz = fmaf(fmaxf(acc[2], 0.0f), w3f[2], pz);
            pz = fmaf(fmaxf(acc[3], 0.0f), w3f[3], pz);
            // reduce over out-blocks (lane groups): lanes {c15, +16, +32, +48}
            pz += __shfl_xor(pz, 16, 64);
            pz += __shfl_xor(pz, 32, 64);
            z[m] = pz;
        }
        // my row = 16*g + c15  ->  z from tile m = g
        const float zz = (g == 0) ? z[0] : (g == 1) ? z[1] : (g == 2) ? z[2] : z[3];
        const float zb = zz + b3v;
        // softplus (stable): max(z,0) + log(1 + exp(-|z|))
        const float beta = fmaxf(zb, 0.0f) + __logf(1.0f + __expf(-fabsf(zb)));
        const float new_inf = beta * s * iv * rcpN;
        const float new_rec = GAMMA * iv;
        s  = s - new_inf;
        iv = iv + new_inf - new_rec;
        r  = r + new_rec;
        return iv;
    };

    const long obase = (long)row * HORIZON;
    #pragma unroll 1
    for (int tt = 0; tt < HORIZON / 4; ++tt) {
        float4 o;
        o.x = step();
        o.y = step();
        o.z = step();
        o.w = step();
        *reinterpret_cast<float4*>(out + obase + tt * 4) = o;
    }
}

extern "C" void kernel_launch(void* const* d_in, const int* in_sizes, int n_in,
                              void* d_out, int out_size, void* d_ws, size_t ws_size,
                              hipStream_t stream) {
    const float* inputs = (const float*)d_in[0];
    const float* W1 = (const float*)d_in[1];
    const float* b1 = (const float*)d_in[2];
    const float* W2 = (const float*)d_in[3];
    const float* b2 = (const float*)d_in[4];
    const float* W3 = (const float*)d_in[5];
    const float* b3 = (const float*)d_in[6];
    float* out = (float*)d_out;

    const int nrows = in_sizes[0] / 24;   // (B, 8, 3) fp32
    const int grid = (nrows + 255) / 256;
    sir_kernel<<<grid, 256, 0, stream>>>(inputs, W1, b1, W2, b2, W3, b3, out, nrows);
}

// Round 6
// 236.096 us; speedup vs baseline: 39.9581x; 1.2656x over previous
//
#include <hip/hip_runtime.h>

#define HORIZON 28
#define GAMMA 0.1f

typedef __attribute__((ext_vector_type(8))) short short8;        // 8 bf16 (4 VGPR) MFMA A/B frag
typedef __attribute__((ext_vector_type(4))) float f32x4;         // MFMA C/D frag
typedef __attribute__((ext_vector_type(4))) unsigned int u32x4;

__global__ void __launch_bounds__(256) sir_kernel(
    const float* __restrict__ inputs,
    const float* __restrict__ W1,
    const float* __restrict__ b1,
    const float* __restrict__ W2,
    const float* __restrict__ b2,
    const float* __restrict__ W3,
    const float* __restrict__ b3,
    float* __restrict__ out,
    int nrows)
{
    __shared__ __align__(16) float sW1[128];    // packed [32][4] = {W1s, W1i, W1r, b1}
    __shared__ __align__(16) f32x4 sState[256]; // [wave][lane] -> {s, i, r, -}, 4 KB

    const int tid  = threadIdx.x;
    const int lane = tid & 63;
    const int wid  = tid >> 6;
    const int g    = lane >> 4;    // lane group = this lane's k-chunk (k = 8g..8g+7)
    const int c15  = lane & 15;    // MFMA col = data row within a 16-row tile

    if (tid < 32) {
        sW1[tid*4+0] = W1[tid];
        sW1[tid*4+1] = W1[32+tid];
        sW1[tid*4+2] = W1[64+tid];
        sW1[tid*4+3] = b1[tid];
    }
    __syncthreads();

    // This lane's 8 W1 columns (k = 8g+j) -> persistent registers (no LDS in hot loop)
    f32x4 wp[8];
    #pragma unroll
    for (int j = 0; j < 8; ++j)
        wp[j] = *reinterpret_cast<const f32x4*>(&sW1[(g*8 + j) * 4]);

    // Persistent A-frags: W2 hi/lo split. lane holds A[out=c15][k=8g+j] = W2[k][c15]
    short8 ahi, alo;
    {
        u32x4 ph, pl;
        #pragma unroll
        for (int jj = 0; jj < 4; ++jj) {
            const float we = W2[(g*8 + 2*jj    )*16 + c15];
            const float wo = W2[(g*8 + 2*jj + 1)*16 + c15];
            const unsigned ue = __float_as_uint(we);
            const unsigned uo = __float_as_uint(wo);
            const float le = we - __uint_as_float(ue & 0xffff0000u);
            const float lo = wo - __uint_as_float(uo & 0xffff0000u);
            ph[jj] = __builtin_amdgcn_perm(uo, ue, 0x07060302u);   // [bf16(we) | bf16(wo)]
            pl[jj] = __builtin_amdgcn_perm(__float_as_uint(lo), __float_as_uint(le), 0x07060302u);
        }
        ahi = __builtin_bit_cast(short8, ph);
        alo = __builtin_bit_cast(short8, pl);
    }
    // C-init (b2) and W3 for this lane's out-block (outs 4g..4g+3)
    const f32x4 b2f = *reinterpret_cast<const f32x4*>(b2 + g*4);
    const f32x4 w3f = *reinterpret_cast<const f32x4*>(W3 + g*4);
    const float b3v = b3[0];

    const int row = blockIdx.x * 256 + tid;
    if (row >= nrows) return;   // never taken at B=2^20 (wave stays intact for MFMA)

    const float* p = inputs + ((long)row * 8 + 7) * 3;
    float s  = p[0];
    float iv = p[1];
    float r  = p[2];
    const float rcpN = 1.0f / (s + iv + r);   // N conserved by SIR update

    f32x4* const stBase = &sState[wid * 64];        // per-wave buffer, no barrier needed
    const f32x4* const stRead = stBase + c15;       // + m*16 selects tile m's row

    auto step = [&]() -> float {
        // stage own state; wave-lockstep + lgkmcnt makes write->read safe without barrier
        f32x4 st; st[0] = s; st[1] = iv; st[2] = r; st[3] = 0.0f;
        stBase[lane] = st;

        float z[4];
        #pragma unroll
        for (int m = 0; m < 4; ++m) {
            const f32x4 sm = stRead[m * 16];   // state of row 16m+c15
            // L1: this lane's 8 h1 values (k=8g+j) for that row
            float h[8];
            #pragma unroll
            for (int j = 0; j < 8; ++j) {
                float v = fmaf(sm[0], wp[j][0], wp[j][3]);
                v = fmaf(sm[1], wp[j][1], v);
                v = fmaf(sm[2], wp[j][2], v);
                h[j] = fmaxf(v, 0.0f);
            }
            // hi/lo truncation split + pack: this IS the B-frag (no LDS round-trip)
            u32x4 ph, pl;
            #pragma unroll
            for (int jj = 0; jj < 4; ++jj) {
                const unsigned ue = __float_as_uint(h[2*jj]);
                const unsigned uo = __float_as_uint(h[2*jj+1]);
                ph[jj] = __builtin_amdgcn_perm(uo, ue, 0x07060302u);
                const float le = h[2*jj]   - __uint_as_float(ue & 0xffff0000u);
                const float lo = h[2*jj+1] - __uint_as_float(uo & 0xffff0000u);
                pl[jj] = __builtin_amdgcn_perm(__float_as_uint(lo), __float_as_uint(le), 0x07060302u);
            }
            const short8 bh = __builtin_bit_cast(short8, ph);
            const short8 bl = __builtin_bit_cast(short8, pl);
            // L2 (hi/lo = fp32-equivalent, identical math to R5)
            f32x4 acc = __builtin_amdgcn_mfma_f32_16x16x32_bf16(ahi, bh, b2f, 0, 0, 0);
            acc = __builtin_amdgcn_mfma_f32_16x16x32_bf16(ahi, bl, acc, 0, 0, 0);
            acc = __builtin_amdgcn_mfma_f32_16x16x32_bf16(alo, bh, acc, 0, 0, 0);
            // L3 partial over this lane's 4 outs, then reduce over lane groups
            float pz = fmaxf(acc[0], 0.0f) * w3f[0];
            pz = fmaf(fmaxf(acc[1], 0.0f), w3f[1], pz);
            pz = fmaf(fmaxf(acc[2], 0.0f), w3f[2], pz);
            pz = fmaf(fmaxf(acc[3], 0.0f), w3f[3], pz);
            pz += __shfl_xor(pz, 16, 64);
            pz += __shfl_xor(pz, 32, 64);
            z[m] = pz;
        }
        // my row = 16g + c15 -> z from tile m == g (g-compares hoist out of the loop)
        const float zz = (g == 0) ? z[0] : (g == 1) ? z[1] : (g == 2) ? z[2] : z[3];
        const float zb = zz + b3v;
        // softplus (stable): max(z,0) + ln2*log2(1 + exp2(-|z|*log2e))
        const float t = __builtin_amdgcn_exp2f(-fabsf(zb) * 1.44269504088896341f);
        const float beta = fmaxf(zb, 0.0f) + 0.69314718055994531f * __builtin_amdgcn_logf(1.0f + t);
        const float new_inf = beta * s * iv * rcpN;
        const float new_rec = GAMMA * iv;
        s  = s - new_inf;
        iv = iv + new_inf - new_rec;
        r  = r + new_rec;
        return iv;
    };

    const long obase = (long)row * HORIZON;
    #pragma unroll 1
    for (int tt = 0; tt < HORIZON / 4; ++tt) {
        float4 o;
        o.x = step();
        o.y = step();
        o.z = step();
        o.w = step();
        *reinterpret_cast<float4*>(out + obase + tt * 4) = o;
    }
}

extern "C" void kernel_launch(void* const* d_in, const int* in_sizes, int n_in,
                              void* d_out, int out_size, void* d_ws, size_t ws_size,
                              hipStream_t stream) {
    const float* inputs = (const float*)d_in[0];
    const float* W1 = (const float*)d_in[1];
    const float* b1 = (const float*)d_in[2];
    const float* W2 = (const float*)d_in[3];
    const float* b2 = (const float*)d_in[4];
    const float* W3 = (const float*)d_in[5];
    const float* b3 = (const float*)d_in[6];
    float* out = (float*)d_out;

    const int nrows = in_sizes[0] / 24;   // (B, 8, 3) fp32
    const int grid = (nrows + 255) / 256;
    sir_kernel<<<grid, 256, 0, stream>>>(inputs, W1, b1, W2, b2, W3, b3, out, nrows);
}

// Round 7
// 198.773 us; speedup vs baseline: 47.4610x; 1.1878x over previous
//
#include <hip/hip_runtime.h>

#define HORIZON 28
#define GAMMA 0.1f

typedef __attribute__((ext_vector_type(8))) _Float16 half8;   // 8 f16 (4 VGPR) MFMA A/B frag
typedef __attribute__((ext_vector_type(2))) _Float16 half2t;
typedef __attribute__((ext_vector_type(4))) float f32x4;      // MFMA C/D frag
typedef __attribute__((ext_vector_type(2))) float fv2;        // packed-fp32 (v_pk_fma_f32) lane pair
typedef __attribute__((ext_vector_type(4))) unsigned int u32x4;

__global__ void __launch_bounds__(256) sir_kernel(
    const float* __restrict__ inputs,
    const float* __restrict__ W1,
    const float* __restrict__ b1,
    const float* __restrict__ W2,
    const float* __restrict__ b2,
    const float* __restrict__ W3,
    const float* __restrict__ b3,
    float* __restrict__ out,
    int nrows)
{
    __shared__ __align__(8) float sWs[32], sWi[32], sWr[32], sWb[32];  // W1 SoA
    __shared__ __align__(16) f32x4 sState[256];   // [wave][lane] -> {s, i, r, -}

    const int tid  = threadIdx.x;
    const int lane = tid & 63;
    const int wid  = tid >> 6;
    const int g    = lane >> 4;    // lane group = this lane's k-chunk (k = 8g..8g+7)
    const int c15  = lane & 15;    // MFMA col = data row within a 16-row tile

    if (tid < 32) {
        sWs[tid] = W1[tid];
        sWi[tid] = W1[32 + tid];
        sWr[tid] = W1[64 + tid];
        sWb[tid] = b1[tid];
    }
    __syncthreads();

    // This lane's 8 W1 columns as float2 pairs -> persistent regs (feeds v_pk_fma_f32)
    fv2 wps[4], wpi[4], wpr[4], wpb[4];
    #pragma unroll
    for (int p = 0; p < 4; ++p) {
        wps[p] = *reinterpret_cast<const fv2*>(&sWs[g*8 + 2*p]);
        wpi[p] = *reinterpret_cast<const fv2*>(&sWi[g*8 + 2*p]);
        wpr[p] = *reinterpret_cast<const fv2*>(&sWr[g*8 + 2*p]);
        wpb[p] = *reinterpret_cast<const fv2*>(&sWb[g*8 + 2*p]);
    }

    // Persistent A-frags: W2 in fp16, hi + lo (residual) split -> near-exact W2.
    // lane holds A[out=c15][k=8g+j] = W2[k][c15]
    half8 ahi, alo;
    {
        u32x4 uh, ul;
        #pragma unroll
        for (int jj = 0; jj < 4; ++jj) {
            const float we = W2[(g*8 + 2*jj    )*16 + c15];
            const float wo = W2[(g*8 + 2*jj + 1)*16 + c15];
            half2t hh; hh[0] = (_Float16)we; hh[1] = (_Float16)wo;       // RNE
            const float rle = we - (float)hh[0];
            const float rlo = wo - (float)hh[1];
            half2t hl; hl[0] = (_Float16)rle; hl[1] = (_Float16)rlo;
            uh[jj] = __builtin_bit_cast(unsigned int, hh);
            ul[jj] = __builtin_bit_cast(unsigned int, hl);
        }
        ahi = __builtin_bit_cast(half8, uh);
        alo = __builtin_bit_cast(half8, ul);
    }
    // C-init (b2) and W3 for this lane's out-block (outs 4g..4g+3)
    const f32x4 b2f = *reinterpret_cast<const f32x4*>(b2 + g*4);
    const fv2 w3p0 = *reinterpret_cast<const fv2*>(W3 + g*4);
    const fv2 w3p1 = *reinterpret_cast<const fv2*>(W3 + g*4 + 2);
    const float b3v = b3[0];

    const int row = blockIdx.x * 256 + tid;
    if (row >= nrows) return;   // never taken at B=2^20 (wave stays intact for MFMA)

    const float* p = inputs + ((long)row * 8 + 7) * 3;
    float s  = p[0];
    float iv = p[1];
    float r  = p[2];
    const float rcpN = 1.0f / (s + iv + r);   // N conserved by SIR update

    f32x4* const stBase = &sState[wid * 64];   // per-wave buffer; same-wave DS is in-order
    const f32x4* const stRead = stBase + c15;  // + m*16 selects tile m's row

    const fv2 zero2 = (fv2){0.0f, 0.0f};

    auto step = [&]() -> float {
        f32x4 st; st[0] = s; st[1] = iv; st[2] = r; st[3] = 0.0f;
        stBase[lane] = st;

        float z[4];
        #pragma unroll
        for (int m = 0; m < 4; ++m) {
            const f32x4 sm = stRead[m * 16];   // state of row 16m+c15
            const fv2 sv  = (fv2){sm[0], sm[0]};
            const fv2 ivv = (fv2){sm[1], sm[1]};
            const fv2 rv  = (fv2){sm[2], sm[2]};
            // L1: 8 h1 values (k=8g+j) as 4 packed-fp32 pairs, then fp16-RTZ pack
            u32x4 ub;
            #pragma unroll
            for (int pp = 0; pp < 4; ++pp) {
                fv2 h = __builtin_elementwise_fma(sv,  wps[pp], wpb[pp]);
                h = __builtin_elementwise_fma(ivv, wpi[pp], h);
                h = __builtin_elementwise_fma(rv,  wpr[pp], h);
                h = __builtin_elementwise_max(h, zero2);
                ub[pp] = __builtin_bit_cast(unsigned int,
                            __builtin_amdgcn_cvt_pkrtz(h[0], h[1]));
            }
            const half8 bh = __builtin_bit_cast(half8, ub);
            // L2: fp16 MFMA, W2 = hi + lo (h1 single fp16)
            f32x4 acc = __builtin_amdgcn_mfma_f32_16x16x32_f16(ahi, bh, b2f, 0, 0, 0);
            acc = __builtin_amdgcn_mfma_f32_16x16x32_f16(alo, bh, acc, 0, 0, 0);
            // L3 partial over this lane's 4 outs (packed), then lane-group reduce
            fv2 a01 = __builtin_shufflevector(acc, acc, 0, 1);
            fv2 a23 = __builtin_shufflevector(acc, acc, 2, 3);
            a01 = __builtin_elementwise_max(a01, zero2);
            a23 = __builtin_elementwise_max(a23, zero2);
            fv2 t = a01 * w3p0;
            t = __builtin_elementwise_fma(a23, w3p1, t);
            float pz = t[0] + t[1];
            pz += __shfl_xor(pz, 16, 64);
            pz += __shfl_xor(pz, 32, 64);
            z[m] = pz;
        }
        // my row = 16g + c15 -> z from tile m == g
        const float zz = (g == 0) ? z[0] : (g == 1) ? z[1] : (g == 2) ? z[2] : z[3];
        const float zb = zz + b3v;
        // softplus (stable): max(z,0) + ln2*log2(1 + exp2(-|z|*log2e))
        const float t = __builtin_amdgcn_exp2f(-fabsf(zb) * 1.44269504088896341f);
        const float beta = fmaxf(zb, 0.0f) + 0.69314718055994531f * __builtin_amdgcn_logf(1.0f + t);
        const float new_inf = beta * s * iv * rcpN;
        const float new_rec = GAMMA * iv;
        s  = s - new_inf;
        iv = iv + new_inf - new_rec;
        r  = r + new_rec;
        return iv;
    };

    const long obase = (long)row * HORIZON;
    #pragma unroll 1
    for (int tt = 0; tt < HORIZON / 4; ++tt) {
        float4 o;
        o.x = step();
        o.y = step();
        o.z = step();
        o.w = step();
        *reinterpret_cast<float4*>(out + obase + tt * 4) = o;
    }
}

extern "C" void kernel_launch(void* const* d_in, const int* in_sizes, int n_in,
                              void* d_out, int out_size, void* d_ws, size_t ws_size,
                              hipStream_t stream) {
    const float* inputs = (const float*)d_in[0];
    const float* W1 = (const float*)d_in[1];
    const float* b1 = (const float*)d_in[2];
    const float* W2 = (const float*)d_in[3];
    const float* b2 = (const float*)d_in[4];
    const float* W3 = (const float*)d_in[5];
    const float* b3 = (const float*)d_in[6];
    float* out = (float*)d_out;

    const int nrows = in_sizes[0] / 24;   // (B, 8, 3) fp32
    const int grid = (nrows + 255) / 256;
    sir_kernel<<<grid, 256, 0, stream>>>(inputs, W1, b1, W2, b2, W3, b3, out, nrows);
}